// Round 1
// baseline (5588.342 us; speedup 1.0000x reference)
//
#include <hip/hip_runtime.h>

#define NS 64
#define NO 32
#define NU 16
#define NT 1024
#define NB 512
#define TCAP 320
#define GROW 112           // floats per G row: M(64) | N(16) | K(32)
#define GROW4 28           // float4 per G row
#define RICCATI_LDS_FLOATS 32256

#define FMA4(acc, s, v) do { float4 _v = (v); float _s = (s); \
  acc.x = fmaf(_s,_v.x,acc.x); acc.y = fmaf(_s,_v.y,acc.y); \
  acc.z = fmaf(_s,_v.z,acc.z); acc.w = fmaf(_s,_v.w,acc.w); } while(0)
#define FNM4(acc, s, v) do { float4 _v = (v); float _s = -(s); \
  acc.x = fmaf(_s,_v.x,acc.x); acc.y = fmaf(_s,_v.y,acc.y); \
  acc.z = fmaf(_s,_v.z,acc.z); acc.w = fmaf(_s,_v.w,acc.w); } while(0)

// ---------------------------------------------------------------------------
// Phase 1: batch-independent Riccati recursion. One block, all LDS.
// Stores G_t = [M_t | N_t | K_t] (row-major, 112 floats/row) for t=0..t_conv,
// where x_t = M_t x_{t-1} + N_t u_t + K_t z_t, and hdr[0] = t_conv.
// ---------------------------------------------------------------------------
__global__ __launch_bounds__(1024) void riccati_kernel(
    const float* __restrict__ Ag, const float* __restrict__ Bg,
    const float* __restrict__ Cg, const float* __restrict__ Qg,
    const float* __restrict__ Rg, float* __restrict__ Gout,
    int* __restrict__ hdr, int tcap)
{
  extern __shared__ float sm[];
  float* Al  = sm;            // [64][64]
  float* Atl = Al  + 4096;    // [64][64]  A^T
  float* Cl  = Atl + 4096;    // [32][64]
  float* CTl = Cl  + 2048;    // [64][32]  C^T
  float* CAl = CTl + 2048;    // [32][64]  C*A
  float* CBl = CAl + 2048;    // [32][16]  C*B
  float* Pl  = CBl + 512;     // [64][64]  current posterior P
  float* Ppl = Pl  + 4096;    // [64][64]  prior P
  float* T1l = Ppl + 4096;    // [64][64]  A*P
  float* CPl = T1l + 4096;    // [32][64]  C*Pp
  float* Kl  = CPl + 2048;    // [64][32]
  float* Sl  = Kl  + 2048;    // [32][32]  S then S^-1
  __shared__ unsigned redmax;
  __shared__ int done;

  const int tid = threadIdx.x;

  // ---- init loads ----
  for (int idx = tid; idx < 4096; idx += 1024) Al[idx] = Ag[idx];
  for (int idx = tid; idx < 2048; idx += 1024) Cl[idx] = Cg[idx];
  for (int idx = tid; idx < 4096; idx += 1024) Pl[idx] = ((idx >> 6) == (idx & 63)) ? 1.f : 0.f;
  for (int idx = tid; idx < 2048; idx += 1024) Kl[idx] = 0.f;
  if (tid == 0) { redmax = 0u; done = 0; }
  __syncthreads();
  for (int idx = tid; idx < 4096; idx += 1024) { int r = idx >> 6, c = idx & 63; Atl[c*64 + r] = Al[idx]; }
  for (int idx = tid; idx < 2048; idx += 1024) { int r = idx >> 6, c = idx & 63; CTl[c*32 + r] = Cl[idx]; }
  __syncthreads();

  // ---- CA = C*A (32x64), CB = C*B (32x16) ----
  if (tid < 512) {
    int i = tid >> 4, j4 = tid & 15;
    const float4* A4 = (const float4*)Al;
    const float4* C4 = (const float4*)Cl;
    float4 acc = make_float4(0,0,0,0);
    #pragma unroll
    for (int k4 = 0; k4 < 16; ++k4) {
      float4 c = C4[i*16 + k4];
      FMA4(acc, c.x, A4[(4*k4+0)*16 + j4]);
      FMA4(acc, c.y, A4[(4*k4+1)*16 + j4]);
      FMA4(acc, c.z, A4[(4*k4+2)*16 + j4]);
      FMA4(acc, c.w, A4[(4*k4+3)*16 + j4]);
    }
    ((float4*)CAl)[i*16 + j4] = acc;
  }
  if (tid < 128) {
    int i = tid >> 2, j4 = tid & 3;
    const float4* B4 = (const float4*)Bg;
    const float4* C4 = (const float4*)Cl;
    float4 acc = make_float4(0,0,0,0);
    #pragma unroll
    for (int k4 = 0; k4 < 16; ++k4) {
      float4 c = C4[i*16 + k4];
      FMA4(acc, c.x, B4[(4*k4+0)*4 + j4]);
      FMA4(acc, c.y, B4[(4*k4+1)*4 + j4]);
      FMA4(acc, c.z, B4[(4*k4+2)*4 + j4]);
      FMA4(acc, c.w, B4[(4*k4+3)*4 + j4]);
    }
    ((float4*)CBl)[i*4 + j4] = acc;
  }
  __syncthreads();

  for (int t = 0; t < tcap; ++t) {
    const int i16 = tid >> 4, j16 = tid & 15;
    // ---- T1 = A * P ----
    {
      const float4* A4 = (const float4*)Al;
      const float4* P4 = (const float4*)Pl;
      float4 acc = make_float4(0,0,0,0);
      #pragma unroll
      for (int k4 = 0; k4 < 16; ++k4) {
        float4 a = A4[i16*16 + k4];
        FMA4(acc, a.x, P4[(4*k4+0)*16 + j16]);
        FMA4(acc, a.y, P4[(4*k4+1)*16 + j16]);
        FMA4(acc, a.z, P4[(4*k4+2)*16 + j16]);
        FMA4(acc, a.w, P4[(4*k4+3)*16 + j16]);
      }
      ((float4*)T1l)[i16*16 + j16] = acc;
    }
    __syncthreads();
    // ---- Pp = T1 * A^T + Q ----
    {
      const float4* T4  = (const float4*)T1l;
      const float4* At4 = (const float4*)Atl;
      float4 acc = ((const float4*)Qg)[i16*16 + j16];
      #pragma unroll
      for (int k4 = 0; k4 < 16; ++k4) {
        float4 a = T4[i16*16 + k4];
        FMA4(acc, a.x, At4[(4*k4+0)*16 + j16]);
        FMA4(acc, a.y, At4[(4*k4+1)*16 + j16]);
        FMA4(acc, a.z, At4[(4*k4+2)*16 + j16]);
        FMA4(acc, a.w, At4[(4*k4+3)*16 + j16]);
      }
      ((float4*)Ppl)[i16*16 + j16] = acc;
    }
    __syncthreads();
    // ---- CP = C * Pp (32x64) ----
    if (tid < 512) {
      const float4* C4  = (const float4*)Cl;
      const float4* Pp4 = (const float4*)Ppl;
      float4 acc = make_float4(0,0,0,0);
      #pragma unroll
      for (int k4 = 0; k4 < 16; ++k4) {
        float4 c = C4[i16*16 + k4];
        FMA4(acc, c.x, Pp4[(4*k4+0)*16 + j16]);
        FMA4(acc, c.y, Pp4[(4*k4+1)*16 + j16]);
        FMA4(acc, c.z, Pp4[(4*k4+2)*16 + j16]);
        FMA4(acc, c.w, Pp4[(4*k4+3)*16 + j16]);
      }
      ((float4*)CPl)[i16*16 + j16] = acc;
    }
    __syncthreads();
    // ---- S = CP * C^T + R (32x32) ----
    if (tid < 256) {
      int i = tid >> 3, j4 = tid & 7;
      const float4* CP4 = (const float4*)CPl;
      const float4* CT4 = (const float4*)CTl;
      float4 acc = ((const float4*)Rg)[i*8 + j4];
      #pragma unroll
      for (int k4 = 0; k4 < 16; ++k4) {
        float4 c = CP4[i*16 + k4];
        FMA4(acc, c.x, CT4[(4*k4+0)*8 + j4]);
        FMA4(acc, c.y, CT4[(4*k4+1)*8 + j4]);
        FMA4(acc, c.z, CT4[(4*k4+2)*8 + j4]);
        FMA4(acc, c.w, CT4[(4*k4+3)*8 + j4]);
      }
      ((float4*)Sl)[i*8 + j4] = acc;
    }
    __syncthreads();
    // ---- Gauss-Jordan inverse of S: single wave, augmented columns in lanes ----
    if (tid < 64) {
      float col[32];
      #pragma unroll
      for (int i = 0; i < 32; ++i)
        col[i] = (tid < 32) ? Sl[i*32 + tid] : ((i == tid - 32) ? 1.f : 0.f);
      #pragma unroll
      for (int k = 0; k < 32; ++k) {
        float fk  = __shfl(col[k], k, 64);
        float pi  = 1.0f / fk;
        float rkp = col[k] * pi;
        #pragma unroll
        for (int i = 0; i < 32; ++i) {
          if (i != k) {
            float fi = __shfl(col[i], k, 64);
            col[i] = fmaf(-fi, rkp, col[i]);
          }
        }
        col[k] = rkp;
      }
      if (tid >= 32) {
        #pragma unroll
        for (int i = 0; i < 32; ++i) Sl[i*32 + (tid - 32)] = col[i];
      }
    }
    __syncthreads();
    // ---- K = (Pp C^T) * Sinv,  Pp C^T = (C Pp)^T (Pp symmetric) ----
    if (tid < 512) {
      int i = tid >> 3, j4 = tid & 7;
      const float4* Si4 = (const float4*)Sl;
      float4 acc = make_float4(0,0,0,0);
      #pragma unroll
      for (int m = 0; m < 32; ++m) FMA4(acc, CPl[m*64 + i], Si4[m*8 + j4]);
      float4* K4 = (float4*)Kl;
      float4 old = K4[i*8 + j4];
      float d = fmaxf(fmaxf(fabsf(acc.x-old.x), fabsf(acc.y-old.y)),
                      fmaxf(fabsf(acc.z-old.z), fabsf(acc.w-old.w)));
      #pragma unroll
      for (int off = 32; off; off >>= 1) d = fmaxf(d, __shfl_xor(d, off, 64));
      if ((tid & 63) == 0) atomicMax(&redmax, __float_as_uint(d));
      K4[i*8 + j4] = acc;
    }
    __syncthreads();
    // ---- P = Pp - K*CP ; M_t = A - K*CA ; N_t = B - K*CB ; store G_t ----
    float4* Gt = (float4*)Gout + (size_t)t * 64 * GROW4;
    {
      const float4* CP4 = (const float4*)CPl;
      const float4* CA4 = (const float4*)CAl;
      float4 accP = ((const float4*)Ppl)[i16*16 + j16];
      float4 accM = ((const float4*)Al)[i16*16 + j16];
      #pragma unroll
      for (int m = 0; m < 32; ++m) {
        float kv = Kl[i16*32 + m];
        FNM4(accP, kv, CP4[m*16 + j16]);
        FNM4(accM, kv, CA4[m*16 + j16]);
      }
      ((float4*)Pl)[i16*16 + j16] = accP;
      Gt[i16*GROW4 + j16] = accM;
    }
    if (tid < 256) {
      int i = tid >> 2, j4 = tid & 3;
      const float4* CB4 = (const float4*)CBl;
      float4 accN = ((const float4*)Bg)[i*4 + j4];
      #pragma unroll
      for (int m = 0; m < 32; ++m) FNM4(accN, Kl[i*32 + m], CB4[m*4 + j4]);
      Gt[i*GROW4 + 16 + j4] = accN;
    }
    if (tid < 512) {
      int i = tid >> 3, j4 = tid & 7;
      Gt[i*GROW4 + 20 + j4] = ((const float4*)Kl)[i*8 + j4];
    }
    __syncthreads();
    if (tid == 0) {
      float d = __uint_as_float(redmax);
      redmax = 0u;
      if (d < 1.5e-4f || t == tcap - 1) { done = 1; hdr[0] = t; }
    }
    __syncthreads();
    if (done) break;
  }
}

// ---------------------------------------------------------------------------
// Phase 2: per-batch state recursion. 1 batch/block, thread = state row.
// G row held in registers; frozen after t_conv.
// ---------------------------------------------------------------------------
__global__ __launch_bounds__(64, 1) void xrec_kernel(
    const float* __restrict__ obs, const float* __restrict__ ins,
    const float* __restrict__ x0, const float* __restrict__ G,
    const int* __restrict__ hdr, float* __restrict__ out)
{
  const int b = blockIdx.x;
  const int i = threadIdx.x;
  const int tconv = hdr[0];
  __shared__ float4 y4[GROW4];          // [ x(64) | u(16) | z(32) ]
  float* y = (float*)y4;

  float xi = x0[i];
  y[i] = xi;
  out[((size_t)b*(NT+1) + 0)*NS + i] = xi;
  if (i < 16)      y[64 + i]        = ins[((size_t)b*NT + 0)*NU + i];
  else if (i < 48) y[80 + (i - 16)] = obs[((size_t)b*NT + 0)*NO + (i - 16)];
  __syncthreads();

  float g[GROW];
  for (int t = 0; t < NT; ++t) {
    if (t <= tconv) {
      const float4* Gr = (const float4*)G + ((size_t)t*64 + i) * GROW4;
      #pragma unroll
      for (int k = 0; k < GROW4; ++k) {
        float4 v = Gr[k];
        g[4*k] = v.x; g[4*k+1] = v.y; g[4*k+2] = v.z; g[4*k+3] = v.w;
      }
    }
    float acc = 0.f;
    #pragma unroll
    for (int k = 0; k < GROW4; ++k) {
      float4 v = y4[k];
      acc = fmaf(g[4*k],   v.x, acc);
      acc = fmaf(g[4*k+1], v.y, acc);
      acc = fmaf(g[4*k+2], v.z, acc);
      acc = fmaf(g[4*k+3], v.w, acc);
    }
    __syncthreads();
    y[i] = acc;
    if (t + 1 < NT) {
      if (i < 16)      y[64 + i]        = ins[((size_t)b*NT + (t+1))*NU + i];
      else if (i < 48) y[80 + (i - 16)] = obs[((size_t)b*NT + (t+1))*NO + (i - 16)];
    }
    out[((size_t)b*(NT+1) + (t+1))*NS + i] = acc;
    __syncthreads();
  }
}

extern "C" void kernel_launch(void* const* d_in, const int* in_sizes, int n_in,
                              void* d_out, int out_size, void* d_ws, size_t ws_size,
                              hipStream_t stream) {
  const float* obs = (const float*)d_in[0];
  const float* ins = (const float*)d_in[1];
  const float* A   = (const float*)d_in[2];
  const float* Bm  = (const float*)d_in[3];
  const float* C   = (const float*)d_in[4];
  const float* Q   = (const float*)d_in[5];
  const float* R   = (const float*)d_in[6];
  const float* x0  = (const float*)d_in[7];
  float* out = (float*)d_out;

  int* hdr = (int*)d_ws;
  float* G = (float*)((char*)d_ws + 256);
  const size_t per_t = (size_t)64 * GROW * sizeof(float);
  int tcap = TCAP;
  if ((size_t)tcap * per_t + 256 > ws_size) tcap = (int)((ws_size - 256) / per_t);
  if (tcap < 1) tcap = 1;

  hipFuncSetAttribute((const void*)riccati_kernel,
                      hipFuncAttributeMaxDynamicSharedMemorySize,
                      RICCATI_LDS_FLOATS * sizeof(float));
  riccati_kernel<<<1, 1024, RICCATI_LDS_FLOATS * sizeof(float), stream>>>(
      A, Bm, C, Q, R, G, hdr, tcap);
  xrec_kernel<<<NB, NS, 0, stream>>>(obs, ins, x0, G, hdr, out);
}

// Round 5
// 4013.316 us; speedup vs baseline: 1.3924x; 1.3924x over previous
//
#include <hip/hip_runtime.h>

#define NS 64
#define NO 32
#define NU 16
#define NT 1024
#define NB 512
#define TCAP 192
#define GROW 112           // floats per G row: M(64) | N(16) | K(32)
#define GROW4 28           // float4 per G row

// LDS float offsets (dynamic shared)
#define OFF_A    0
#define OFF_AT   4096
#define OFF_C    8192
#define OFF_CT   10240
#define OFF_CA   12288
#define OFF_CB   14336
#define OFF_B    14848
#define OFF_Q    15872
#define OFF_R    19968
#define OFF_P    20992
#define OFF_PP   25088
#define OFF_X    29184     // 64x64: T1 scratch, then GJ buffer A (uses 32x64)
#define OFF_X2   33280     // 32x64: GJ buffer B
#define OFF_CP   35328
#define OFF_K    37376
#define OFF_DB   39424
#define LDS_FLOATS 39456

#define FMA4(acc, s, v) do { float4 _v = (v); float _s = (s); \
  acc.x = fmaf(_s,_v.x,acc.x); acc.y = fmaf(_s,_v.y,acc.y); \
  acc.z = fmaf(_s,_v.z,acc.z); acc.w = fmaf(_s,_v.w,acc.w); } while(0)
#define FNM4(acc, s, v) do { float4 _v = (v); float _s = -(s); \
  acc.x = fmaf(_s,_v.x,acc.x); acc.y = fmaf(_s,_v.y,acc.y); \
  acc.z = fmaf(_s,_v.z,acc.z); acc.w = fmaf(_s,_v.w,acc.w); } while(0)

// One unnormalized Gauss-Jordan elimination step (src -> dst), row gi, cols gj+16m.
// Pivot row copied unscaled; division deferred to diagonal-reciprocal pass.
#define GJ_STEP(SRC, DST, KK) do { \
  const float* _s = (SRC); float* _d = (DST); const int _k = (KK); \
  float prcp = 1.0f / _s[_k*64 + _k]; \
  float f  = _s[gi*64 + _k] * prcp; \
  float p0 = _s[_k*64 + gj],      p1 = _s[_k*64 + 16 + gj]; \
  float p2 = _s[_k*64 + 32 + gj], p3 = _s[_k*64 + 48 + gj]; \
  float x0 = _s[gi*64 + gj],      x1 = _s[gi*64 + 16 + gj]; \
  float x2 = _s[gi*64 + 32 + gj], x3 = _s[gi*64 + 48 + gj]; \
  bool piv = (gi == _k); \
  _d[gi*64 + gj]      = piv ? x0 : fmaf(-f, p0, x0); \
  _d[gi*64 + 16 + gj] = piv ? x1 : fmaf(-f, p1, x1); \
  _d[gi*64 + 32 + gj] = piv ? x2 : fmaf(-f, p2, x2); \
  _d[gi*64 + 48 + gj] = piv ? x3 : fmaf(-f, p3, x3); \
} while(0)

// ---------------------------------------------------------------------------
// Phase 1: batch-independent Riccati recursion. One block, 512 threads.
// Small code body (rolled loops) to stay inside the 32 KB L1I.
// ---------------------------------------------------------------------------
__global__ __launch_bounds__(512) void riccati_kernel(
    const float* __restrict__ Ag, const float* __restrict__ Bg,
    const float* __restrict__ Cg, const float* __restrict__ Qg,
    const float* __restrict__ Rg, float* __restrict__ Gout,
    int* __restrict__ hdr, int tcap)
{
  extern __shared__ float sm[];
  float* Al  = sm + OFF_A;
  float* Atl = sm + OFF_AT;
  float* Cl  = sm + OFF_C;
  float* CTl = sm + OFF_CT;
  float* CAl = sm + OFF_CA;
  float* CBl = sm + OFF_CB;
  float* Bl  = sm + OFF_B;
  float* Ql  = sm + OFF_Q;
  float* Rl  = sm + OFF_R;
  float* Pl  = sm + OFF_P;
  float* Ppl = sm + OFF_PP;
  float* Xl  = sm + OFF_X;
  float* X2l = sm + OFF_X2;
  float* CPl = sm + OFF_CP;
  float* Kl  = sm + OFF_K;
  float* db  = sm + OFF_DB;
  __shared__ unsigned redmax;
  __shared__ int done;

  const int tid = threadIdx.x;

  // ---- init loads ----
  for (int x = tid; x < 4096; x += 512) Al[x] = Ag[x];
  for (int x = tid; x < 2048; x += 512) Cl[x] = Cg[x];
  for (int x = tid; x < 1024; x += 512) Bl[x] = Bg[x];
  for (int x = tid; x < 4096; x += 512) Ql[x] = Qg[x];
  for (int x = tid; x < 1024; x += 512) Rl[x] = Rg[x];
  for (int x = tid; x < 4096; x += 512) Pl[x] = ((x >> 6) == (x & 63)) ? 1.f : 0.f;
  for (int x = tid; x < 2048; x += 512) Kl[x] = 0.f;
  if (tid == 0) { redmax = 0u; done = 0; }
  __syncthreads();
  for (int x = tid; x < 4096; x += 512) Atl[(x & 63)*64 + (x >> 6)] = Al[x];
  for (int x = tid; x < 2048; x += 512) CTl[(x & 63)*32 + (x >> 6)] = Cl[x];
  __syncthreads();

  const int r0  = tid >> 4;     // 0..31
  const int r1  = r0 + 32;
  const int j16 = tid & 15;
  const int gi  = r0;           // GJ row
  const int gj  = j16;          // GJ col base
  const float4* A4  = (const float4*)Al;
  const float4* At4 = (const float4*)Atl;
  const float4* C4  = (const float4*)Cl;
  const float4* CT4 = (const float4*)CTl;
  const float4* CA4 = (const float4*)CAl;
  const float4* CB4 = (const float4*)CBl;
  const float4* B4  = (const float4*)Bl;
  const float4* Q4  = (const float4*)Ql;
  const float4* R4  = (const float4*)Rl;
  float4* P4   = (float4*)Pl;
  float4* Pp4  = (float4*)Ppl;
  float4* X4   = (float4*)Xl;
  float4* CP4v = (float4*)CPl;
  float4* K4   = (float4*)Kl;

  // ---- CA = C*A (32x64), CB = C*B (32x16) ----
  {
    float4 acc = make_float4(0,0,0,0);
    #pragma unroll 2
    for (int k4 = 0; k4 < 16; ++k4) {
      float4 c = C4[r0*16 + k4];
      FMA4(acc, c.x, A4[(4*k4+0)*16 + j16]);
      FMA4(acc, c.y, A4[(4*k4+1)*16 + j16]);
      FMA4(acc, c.z, A4[(4*k4+2)*16 + j16]);
      FMA4(acc, c.w, A4[(4*k4+3)*16 + j16]);
    }
    ((float4*)CAl)[tid] = acc;
  }
  if (tid < 128) {
    int i = tid >> 2, j4 = tid & 3;
    float4 acc = make_float4(0,0,0,0);
    #pragma unroll 2
    for (int k4 = 0; k4 < 16; ++k4) {
      float4 c = C4[i*16 + k4];
      FMA4(acc, c.x, B4[(4*k4+0)*4 + j4]);
      FMA4(acc, c.y, B4[(4*k4+1)*4 + j4]);
      FMA4(acc, c.z, B4[(4*k4+2)*4 + j4]);
      FMA4(acc, c.w, B4[(4*k4+3)*4 + j4]);
    }
    ((float4*)CBl)[tid] = acc;
  }
  __syncthreads();

  #pragma unroll 1
  for (int t = 0; t < tcap; ++t) {
    // ---- T1 = A*P -> Xl ----
    {
      float4 acc0 = make_float4(0,0,0,0), acc1 = make_float4(0,0,0,0);
      #pragma unroll 2
      for (int k4 = 0; k4 < 16; ++k4) {
        float4 a0 = A4[r0*16 + k4];
        float4 a1 = A4[r1*16 + k4];
        float4 p0 = P4[(4*k4+0)*16 + j16];
        float4 p1 = P4[(4*k4+1)*16 + j16];
        float4 p2 = P4[(4*k4+2)*16 + j16];
        float4 p3 = P4[(4*k4+3)*16 + j16];
        FMA4(acc0, a0.x, p0); FMA4(acc0, a0.y, p1); FMA4(acc0, a0.z, p2); FMA4(acc0, a0.w, p3);
        FMA4(acc1, a1.x, p0); FMA4(acc1, a1.y, p1); FMA4(acc1, a1.z, p2); FMA4(acc1, a1.w, p3);
      }
      X4[r0*16 + j16] = acc0;
      X4[r1*16 + j16] = acc1;
    }
    __syncthreads();
    // ---- Pp = T1*A^T + Q ----
    {
      float4 acc0 = Q4[r0*16 + j16];
      float4 acc1 = Q4[r1*16 + j16];
      #pragma unroll 2
      for (int k4 = 0; k4 < 16; ++k4) {
        float4 a0 = X4[r0*16 + k4];
        float4 a1 = X4[r1*16 + k4];
        float4 p0 = At4[(4*k4+0)*16 + j16];
        float4 p1 = At4[(4*k4+1)*16 + j16];
        float4 p2 = At4[(4*k4+2)*16 + j16];
        float4 p3 = At4[(4*k4+3)*16 + j16];
        FMA4(acc0, a0.x, p0); FMA4(acc0, a0.y, p1); FMA4(acc0, a0.z, p2); FMA4(acc0, a0.w, p3);
        FMA4(acc1, a1.x, p0); FMA4(acc1, a1.y, p1); FMA4(acc1, a1.z, p2); FMA4(acc1, a1.w, p3);
      }
      Pp4[r0*16 + j16] = acc0;
      Pp4[r1*16 + j16] = acc1;
    }
    __syncthreads();
    // ---- CP = C*Pp (32x64) ----
    {
      float4 acc = make_float4(0,0,0,0);
      #pragma unroll 2
      for (int k4 = 0; k4 < 16; ++k4) {
        float4 c = C4[r0*16 + k4];
        FMA4(acc, c.x, Pp4[(4*k4+0)*16 + j16]);
        FMA4(acc, c.y, Pp4[(4*k4+1)*16 + j16]);
        FMA4(acc, c.z, Pp4[(4*k4+2)*16 + j16]);
        FMA4(acc, c.w, Pp4[(4*k4+3)*16 + j16]);
      }
      CP4v[tid] = acc;
    }
    __syncthreads();
    // ---- S -> X left half ; identity -> X right half ----
    if (tid < 256) {
      int i = tid >> 3, j4 = tid & 7;
      float4 acc = R4[i*8 + j4];
      #pragma unroll 2
      for (int k4 = 0; k4 < 16; ++k4) {
        float4 c = CP4v[i*16 + k4];
        FMA4(acc, c.x, CT4[(4*k4+0)*8 + j4]);
        FMA4(acc, c.y, CT4[(4*k4+1)*8 + j4]);
        FMA4(acc, c.z, CT4[(4*k4+2)*8 + j4]);
        FMA4(acc, c.w, CT4[(4*k4+3)*8 + j4]);
      }
      X4[i*16 + j4] = acc;
    } else {
      int z = tid - 256;
      int i = z >> 3, j4 = z & 7;
      float4 idv;
      idv.x = (i == j4*4+0) ? 1.f : 0.f;
      idv.y = (i == j4*4+1) ? 1.f : 0.f;
      idv.z = (i == j4*4+2) ? 1.f : 0.f;
      idv.w = (i == j4*4+3) ? 1.f : 0.f;
      X4[i*16 + 8 + j4] = idv;
    }
    __syncthreads();
    // ---- Gauss-Jordan: 32 rolled ping-pong steps, 1 barrier each ----
    #pragma unroll 1
    for (int k = 0; k < 32; k += 2) {
      GJ_STEP(Xl, X2l, k);
      __syncthreads();
      GJ_STEP(X2l, Xl, k + 1);
      __syncthreads();
    }
    if (tid < 32) db[tid] = 1.0f / Xl[tid*64 + tid];
    __syncthreads();
    // ---- K = (Pp C^T) * Sinv, Sinv row m = X_right[m] * db[m]; + delta ----
    {
      int i = tid >> 3, j4 = tid & 7;      // i 0..63
      float4 acc = make_float4(0,0,0,0);
      #pragma unroll 4
      for (int m = 0; m < 32; ++m) {
        float w = CPl[m*64 + i] * db[m];
        FMA4(acc, w, X4[m*16 + 8 + j4]);
      }
      float4 old = K4[i*8 + j4];
      float d = fmaxf(fmaxf(fabsf(acc.x-old.x), fabsf(acc.y-old.y)),
                      fmaxf(fabsf(acc.z-old.z), fabsf(acc.w-old.w)));
      #pragma unroll
      for (int off = 32; off; off >>= 1) d = fmaxf(d, __shfl_xor(d, off, 64));
      if ((tid & 63) == 0) atomicMax(&redmax, __float_as_uint(d));
      K4[i*8 + j4] = acc;
    }
    __syncthreads();
    // ---- P = Pp - K*CP ; M = A - K*CA ; N = B - K*CB ; store G_t ----
    float4* Gt = (float4*)Gout + (size_t)t * (64*GROW4);
    {
      float4 accP0 = Pp4[r0*16+j16], accM0 = A4[r0*16+j16];
      float4 accP1 = Pp4[r1*16+j16], accM1 = A4[r1*16+j16];
      #pragma unroll 4
      for (int m = 0; m < 32; ++m) {
        float k0 = Kl[r0*32 + m];
        float k1 = Kl[r1*32 + m];
        float4 cp = CP4v[m*16 + j16];
        float4 ca = CA4[m*16 + j16];
        FNM4(accP0, k0, cp); FNM4(accM0, k0, ca);
        FNM4(accP1, k1, cp); FNM4(accM1, k1, ca);
      }
      P4[r0*16+j16] = accP0;
      P4[r1*16+j16] = accP1;
      Gt[r0*GROW4 + j16] = accM0;
      Gt[r1*GROW4 + j16] = accM1;
    }
    if (tid < 256) {
      int i = tid >> 2, j4 = tid & 3;
      float4 accN = B4[i*4 + j4];
      #pragma unroll 4
      for (int m = 0; m < 32; ++m) FNM4(accN, Kl[i*32 + m], CB4[m*4 + j4]);
      Gt[i*GROW4 + 16 + j4] = accN;
    } else {
      int z = tid - 256;
      int i = z >> 3, j4 = z & 7;
      Gt[i*GROW4 + 20 + j4]      = K4[i*8 + j4];
      Gt[(i+32)*GROW4 + 20 + j4] = K4[(i+32)*8 + j4];
    }
    __syncthreads();
    if (tid == 0) {
      float dmax = __uint_as_float(redmax);
      redmax = 0u;
      if (dmax < 1.5e-4f || t == tcap - 1) { done = 1; hdr[0] = t; }
    }
    __syncthreads();
    if (done) break;
  }
}

// ---------------------------------------------------------------------------
// Phase 2: per-batch state recursion. 1 batch/block, thread = state row.
// Ping-pong y buffer (1 barrier/step), 4 fma chains, early u/z issue.
// ---------------------------------------------------------------------------
#define XSTEP(T, CUR, NXT) do { \
  const int t_ = (T); \
  float uin = 0.f, zin = 0.f; \
  if (t_ + 1 < NT) { \
    if (i < 16)      uin = ins[((size_t)b*NT + t_ + 1)*NU + i]; \
    else if (i < 48) zin = obs[((size_t)b*NT + t_ + 1)*NO + (i - 16)]; \
  } \
  if (t_ <= tconv) { \
    const float4* Gr = (const float4*)G + ((size_t)t_*64 + i)*GROW4; \
    _Pragma("unroll") \
    for (int k = 0; k < GROW4; ++k) g[k] = Gr[k]; \
  } \
  float a0 = 0.f, a1 = 0.f, a2 = 0.f, a3 = 0.f; \
  _Pragma("unroll") \
  for (int k = 0; k < GROW4; k += 4) { \
    float4 v0 = (CUR)[k], v1 = (CUR)[k+1], v2 = (CUR)[k+2], v3 = (CUR)[k+3]; \
    a0 = fmaf(g[k].x,   v0.x, a0); a0 = fmaf(g[k].y,   v0.y, a0); \
    a0 = fmaf(g[k].z,   v0.z, a0); a0 = fmaf(g[k].w,   v0.w, a0); \
    a1 = fmaf(g[k+1].x, v1.x, a1); a1 = fmaf(g[k+1].y, v1.y, a1); \
    a1 = fmaf(g[k+1].z, v1.z, a1); a1 = fmaf(g[k+1].w, v1.w, a1); \
    a2 = fmaf(g[k+2].x, v2.x, a2); a2 = fmaf(g[k+2].y, v2.y, a2); \
    a2 = fmaf(g[k+2].z, v2.z, a2); a2 = fmaf(g[k+2].w, v2.w, a2); \
    a3 = fmaf(g[k+3].x, v3.x, a3); a3 = fmaf(g[k+3].y, v3.y, a3); \
    a3 = fmaf(g[k+3].z, v3.z, a3); a3 = fmaf(g[k+3].w, v3.w, a3); \
  } \
  float acc = (a0 + a1) + (a2 + a3); \
  float* ny = (float*)(NXT); \
  ny[i] = acc; \
  if (i < 16) ny[64 + i] = uin; else if (i < 48) ny[80 + (i - 16)] = zin; \
  out[((size_t)b*(NT+1) + t_ + 1)*NS + i] = acc; \
  __syncthreads(); \
} while(0)

__global__ __launch_bounds__(64) void xrec_kernel(
    const float* __restrict__ obs, const float* __restrict__ ins,
    const float* __restrict__ x0, const float* __restrict__ G,
    const int* __restrict__ hdr, float* __restrict__ out)
{
  const int b = blockIdx.x;
  const int i = threadIdx.x;
  const int tconv = hdr[0];
  __shared__ float4 y4[2][GROW4];
  float* y0 = (float*)y4[0];

  float xi = x0[i];
  y0[i] = xi;
  out[(size_t)b*(NT+1)*NS + i] = xi;
  if (i < 16)      y0[64 + i]        = ins[(size_t)b*NT*NU + i];
  else if (i < 48) y0[80 + (i - 16)] = obs[(size_t)b*NT*NO + (i - 16)];
  __syncthreads();

  float4 g[GROW4];
  #pragma unroll 1
  for (int t = 0; t < NT; t += 2) {
    XSTEP(t,     y4[0], y4[1]);
    XSTEP(t + 1, y4[1], y4[0]);
  }
}

extern "C" void kernel_launch(void* const* d_in, const int* in_sizes, int n_in,
                              void* d_out, int out_size, void* d_ws, size_t ws_size,
                              hipStream_t stream) {
  const float* obs = (const float*)d_in[0];
  const float* ins = (const float*)d_in[1];
  const float* A   = (const float*)d_in[2];
  const float* Bm  = (const float*)d_in[3];
  const float* C   = (const float*)d_in[4];
  const float* Q   = (const float*)d_in[5];
  const float* R   = (const float*)d_in[6];
  const float* x0  = (const float*)d_in[7];
  float* out = (float*)d_out;

  int* hdr = (int*)d_ws;
  float* G = (float*)((char*)d_ws + 256);
  const size_t per_t = (size_t)64 * GROW * sizeof(float);
  int tcap = TCAP;
  if ((size_t)tcap * per_t + 256 > ws_size) tcap = (int)((ws_size - 256) / per_t);
  if (tcap < 1) tcap = 1;

  hipFuncSetAttribute((const void*)riccati_kernel,
                      hipFuncAttributeMaxDynamicSharedMemorySize,
                      LDS_FLOATS * sizeof(float));
  riccati_kernel<<<1, 512, LDS_FLOATS * sizeof(float), stream>>>(
      A, Bm, C, Q, R, G, hdr, tcap);
  xrec_kernel<<<NB, NS, 0, stream>>>(obs, ins, x0, G, hdr, out);
}

// Round 7
// 3272.500 us; speedup vs baseline: 1.7077x; 1.2264x over previous
//
#include <hip/hip_runtime.h>

#define NS 64
#define NO 32
#define NU 16
#define NT 1024
#define NB 512
#define TCAP 64            // G slots; forced freeze at t=63
#define NCH 16             // chunks of 64 steps
#define GROW 112           // floats per G row: M(64) | N(16) | K(32)
#define GROW4 28

// ws byte offsets
#define WS_G    256
#define WS_G_SZ (64*64*112*4)            // 1,835,008
#define WS_M64  (WS_G + WS_G_SZ)         // 1,835,264
#define WS_D    (WS_M64 + 16384)         // 1,851,648
#define WS_D_SZ (NCH*NB*NS*4)            // 8,388,608
#define NEED_FULL (WS_D + WS_D_SZ)
#define NEED_G    (WS_G + WS_G_SZ)

// riccati LDS float offsets
#define OFF_A    0
#define OFF_AT   4096
#define OFF_C    8192
#define OFF_CT   10240
#define OFF_CA   12288
#define OFF_CB   14336
#define OFF_B    14848
#define OFF_R    15872
#define OFF_P    16896
#define OFF_PP   20992
#define OFF_X    25088     // T1 scratch; frozen-M mirror; M64 ping
#define OFF_CP   29184
#define OFF_K    31232
#define OFF_S    33280     // 32x36 padded
#define OFF_XA   34432     // 32x36
#define OFF_XB   35584     // 32x36
#define OFF_E    36736     // 32x36
#define LDS_FLOATS 37888

#define FMA4(acc, s, v) do { float4 _v = (v); float _s = (s); \
  acc.x = fmaf(_s,_v.x,acc.x); acc.y = fmaf(_s,_v.y,acc.y); \
  acc.z = fmaf(_s,_v.z,acc.z); acc.w = fmaf(_s,_v.w,acc.w); } while(0)
#define FNM4(acc, s, v) do { float4 _v = (v); float _s = -(s); \
  acc.x = fmaf(_s,_v.x,acc.x); acc.y = fmaf(_s,_v.y,acc.y); \
  acc.z = fmaf(_s,_v.z,acc.z); acc.w = fmaf(_s,_v.w,acc.w); } while(0)

// ---------------------------------------------------------------------------
// Phase 1: Riccati. One block, 512 threads. Newton-Schulz inverse (warm
// started) instead of Gauss-Jordan: ~11 barriers/iter instead of ~42.
// ---------------------------------------------------------------------------
__global__ __launch_bounds__(512) void riccati_kernel(
    const float* __restrict__ Ag, const float* __restrict__ Bg,
    const float* __restrict__ Cg, const float* __restrict__ Qg,
    const float* __restrict__ Rg, float* __restrict__ Gout,
    float* __restrict__ M64g, int* __restrict__ hdr, int tcap)
{
  extern __shared__ float sm[];
  float* Al  = sm + OFF_A;
  float* Atl = sm + OFF_AT;
  float* Cl  = sm + OFF_C;
  float* CTl = sm + OFF_CT;
  float* CAl = sm + OFF_CA;
  float* CBl = sm + OFF_CB;
  float* Bl  = sm + OFF_B;
  float* Rl  = sm + OFF_R;
  float* Pl  = sm + OFF_P;
  float* Ppl = sm + OFF_PP;
  float* Xl  = sm + OFF_X;
  float* CPl = sm + OFF_CP;
  float* Kl  = sm + OFF_K;
  float* Sl  = sm + OFF_S;
  float* Xa_ = sm + OFF_XA;
  float* Xb_ = sm + OFF_XB;
  float* El  = sm + OFF_E;
  __shared__ unsigned redmax, lmax_u;
  __shared__ int done;

  const int tid = threadIdx.x;

  for (int x = tid; x < 4096; x += 512) Al[x] = Ag[x];
  for (int x = tid; x < 2048; x += 512) Cl[x] = Cg[x];
  for (int x = tid; x < 1024; x += 512) Bl[x] = Bg[x];
  for (int x = tid; x < 1024; x += 512) Rl[x] = Rg[x];
  for (int x = tid; x < 4096; x += 512) Pl[x] = ((x >> 6) == (x & 63)) ? 1.f : 0.f;
  for (int x = tid; x < 2048; x += 512) Kl[x] = 0.f;
  if (tid == 0) { redmax = 0u; lmax_u = 0u; done = 0; }
  __syncthreads();
  for (int x = tid; x < 4096; x += 512) Atl[(x & 63)*64 + (x >> 6)] = Al[x];
  for (int x = tid; x < 2048; x += 512) CTl[(x & 63)*32 + (x >> 6)] = Cl[x];
  __syncthreads();

  const int r0  = tid >> 4;     // 0..31
  const int r1  = r0 + 32;
  const int j16 = tid & 15;
  const float4* A4  = (const float4*)Al;
  const float4* At4 = (const float4*)Atl;
  const float4* C4  = (const float4*)Cl;
  const float4* CT4 = (const float4*)CTl;
  const float4* CA4 = (const float4*)CAl;
  const float4* CB4 = (const float4*)CBl;
  const float4* B4  = (const float4*)Bl;
  const float4* Q4  = (const float4*)Qg;     // global (L2-hot)
  const float4* R4  = (const float4*)Rl;
  float4* P4   = (float4*)Pl;
  float4* Pp4  = (float4*)Ppl;
  float4* X4   = (float4*)Xl;
  float4* CP4v = (float4*)CPl;
  float4* K4   = (float4*)Kl;

  // CA = C*A, CB = C*B
  {
    float4 acc = make_float4(0,0,0,0);
    #pragma unroll 2
    for (int k4 = 0; k4 < 16; ++k4) {
      float4 c = C4[r0*16 + k4];
      FMA4(acc, c.x, A4[(4*k4+0)*16 + j16]);
      FMA4(acc, c.y, A4[(4*k4+1)*16 + j16]);
      FMA4(acc, c.z, A4[(4*k4+2)*16 + j16]);
      FMA4(acc, c.w, A4[(4*k4+3)*16 + j16]);
    }
    ((float4*)CAl)[tid] = acc;
  }
  if (tid < 128) {
    int i = tid >> 2, j4 = tid & 3;
    float4 acc = make_float4(0,0,0,0);
    #pragma unroll 2
    for (int k4 = 0; k4 < 16; ++k4) {
      float4 c = C4[i*16 + k4];
      FMA4(acc, c.x, B4[(4*k4+0)*4 + j4]);
      FMA4(acc, c.y, B4[(4*k4+1)*4 + j4]);
      FMA4(acc, c.z, B4[(4*k4+2)*4 + j4]);
      FMA4(acc, c.w, B4[(4*k4+3)*4 + j4]);
    }
    ((float4*)CBl)[tid] = acc;
  }
  __syncthreads();

  #pragma unroll 1
  for (int t = 0; t < tcap; ++t) {
    // T1 = A*P -> Xl
    {
      float4 acc0 = make_float4(0,0,0,0), acc1 = make_float4(0,0,0,0);
      #pragma unroll 2
      for (int k4 = 0; k4 < 16; ++k4) {
        float4 a0 = A4[r0*16 + k4];
        float4 a1 = A4[r1*16 + k4];
        float4 p0 = P4[(4*k4+0)*16 + j16];
        float4 p1 = P4[(4*k4+1)*16 + j16];
        float4 p2 = P4[(4*k4+2)*16 + j16];
        float4 p3 = P4[(4*k4+3)*16 + j16];
        FMA4(acc0, a0.x, p0); FMA4(acc0, a0.y, p1); FMA4(acc0, a0.z, p2); FMA4(acc0, a0.w, p3);
        FMA4(acc1, a1.x, p0); FMA4(acc1, a1.y, p1); FMA4(acc1, a1.z, p2); FMA4(acc1, a1.w, p3);
      }
      X4[r0*16 + j16] = acc0;
      X4[r1*16 + j16] = acc1;
    }
    __syncthreads();
    // Pp = T1*A^T + Q
    {
      float4 acc0 = Q4[r0*16 + j16];
      float4 acc1 = Q4[r1*16 + j16];
      #pragma unroll 2
      for (int k4 = 0; k4 < 16; ++k4) {
        float4 a0 = X4[r0*16 + k4];
        float4 a1 = X4[r1*16 + k4];
        float4 p0 = At4[(4*k4+0)*16 + j16];
        float4 p1 = At4[(4*k4+1)*16 + j16];
        float4 p2 = At4[(4*k4+2)*16 + j16];
        float4 p3 = At4[(4*k4+3)*16 + j16];
        FMA4(acc0, a0.x, p0); FMA4(acc0, a0.y, p1); FMA4(acc0, a0.z, p2); FMA4(acc0, a0.w, p3);
        FMA4(acc1, a1.x, p0); FMA4(acc1, a1.y, p1); FMA4(acc1, a1.z, p2); FMA4(acc1, a1.w, p3);
      }
      Pp4[r0*16 + j16] = acc0;
      Pp4[r1*16 + j16] = acc1;
    }
    __syncthreads();
    // CP = C*Pp
    {
      float4 acc = make_float4(0,0,0,0);
      #pragma unroll 2
      for (int k4 = 0; k4 < 16; ++k4) {
        float4 c = C4[r0*16 + k4];
        FMA4(acc, c.x, Pp4[(4*k4+0)*16 + j16]);
        FMA4(acc, c.y, Pp4[(4*k4+1)*16 + j16]);
        FMA4(acc, c.z, Pp4[(4*k4+2)*16 + j16]);
        FMA4(acc, c.w, Pp4[(4*k4+3)*16 + j16]);
      }
      CP4v[tid] = acc;
    }
    __syncthreads();
    // S = CP*C^T + R  (32x32, padded stride 36)
    if (tid < 256) {
      int i = tid >> 3, j4 = tid & 7;
      float4 acc = R4[i*8 + j4];
      #pragma unroll 2
      for (int k4 = 0; k4 < 16; ++k4) {
        float4 c = CP4v[i*16 + k4];
        FMA4(acc, c.x, CT4[(4*k4+0)*8 + j4]);
        FMA4(acc, c.y, CT4[(4*k4+1)*8 + j4]);
        FMA4(acc, c.z, CT4[(4*k4+2)*8 + j4]);
        FMA4(acc, c.w, CT4[(4*k4+3)*8 + j4]);
      }
      ((float4*)Sl)[i*9 + j4] = acc;
    }
    __syncthreads();
    // Newton-Schulz inverse, warm-started
    if (t == 0) {
      if (tid < 32) {
        float s = 0.f;
        #pragma unroll 4
        for (int k = 0; k < 32; ++k) s += fabsf(Sl[tid*36 + k]);
        atomicMax(&lmax_u, __float_as_uint(s));
      }
      __syncthreads();
      float inv = 1.0f / __uint_as_float(lmax_u);
      for (int x = tid; x < 1024; x += 512) {
        int r = x >> 5, cc = x & 31;
        Xa_[r*36 + cc] = (r == cc) ? inv : 0.f;
      }
      __syncthreads();
    }
    {
      int nsteps = (t == 0) ? 12 : (t < 3 ? 8 : (t < 8 ? 4 : 2));
      float* Xc = Xa_;
      float* Xn = Xb_;
      #pragma unroll 1
      for (int it = 0; it < nsteps; ++it) {
        if (tid < 256) {                       // E = S*Xc
          int i = tid >> 3, j4 = tid & 7;
          float4 acc = make_float4(0,0,0,0);
          #pragma unroll 4
          for (int k = 0; k < 32; ++k) FMA4(acc, Sl[i*36 + k], ((float4*)Xc)[k*9 + j4]);
          ((float4*)El)[i*9 + j4] = acc;
        }
        __syncthreads();
        if (tid < 256) {                       // Xn = 2*Xc - Xc*E
          int i = tid >> 3, j4 = tid & 7;
          float4 x2 = ((float4*)Xc)[i*9 + j4];
          float4 acc = make_float4(2.f*x2.x, 2.f*x2.y, 2.f*x2.z, 2.f*x2.w);
          #pragma unroll 4
          for (int k = 0; k < 32; ++k) FNM4(acc, Xc[i*36 + k], ((float4*)El)[k*9 + j4]);
          ((float4*)Xn)[i*9 + j4] = acc;
        }
        __syncthreads();
        float* tmp = Xc; Xc = Xn; Xn = tmp;
      }
    }
    // K = (CP)^T * Sinv ; convergence delta
    {
      int i = tid >> 3, j4 = tid & 7;          // i 0..63
      const float4* Si4 = (const float4*)Xa_;  // nsteps even -> result in Xa_
      float4 acc = make_float4(0,0,0,0);
      #pragma unroll 4
      for (int m = 0; m < 32; ++m) FMA4(acc, CPl[m*64 + i], Si4[m*9 + j4]);
      float4 old = K4[i*8 + j4];
      float d = fmaxf(fmaxf(fabsf(acc.x-old.x), fabsf(acc.y-old.y)),
                      fmaxf(fabsf(acc.z-old.z), fabsf(acc.w-old.w)));
      #pragma unroll
      for (int off = 32; off; off >>= 1) d = fmaxf(d, __shfl_xor(d, off, 64));
      if ((tid & 63) == 0) atomicMax(&redmax, __float_as_uint(d));
      K4[i*8 + j4] = acc;
    }
    __syncthreads();
    if (tid == 0) {
      float dmax = __uint_as_float(redmax);
      redmax = 0u;
      if (dmax < 6e-4f || t == tcap - 1) { done = 1; hdr[0] = t; }
    }
    __syncthreads();
    // P = Pp - K*CP ; M = A - K*CA ; N = B - K*CB ; store G_t
    float4* Gt = (float4*)Gout + (size_t)t * (64*GROW4);
    {
      float4 accP0 = Pp4[r0*16+j16], accM0 = A4[r0*16+j16];
      float4 accP1 = Pp4[r1*16+j16], accM1 = A4[r1*16+j16];
      #pragma unroll 4
      for (int m = 0; m < 32; ++m) {
        float k0 = Kl[r0*32 + m];
        float k1 = Kl[r1*32 + m];
        float4 cp = CP4v[m*16 + j16];
        float4 ca = CA4[m*16 + j16];
        FNM4(accP0, k0, cp); FNM4(accM0, k0, ca);
        FNM4(accP1, k1, cp); FNM4(accM1, k1, ca);
      }
      P4[r0*16+j16] = accP0;
      P4[r1*16+j16] = accP1;
      Gt[r0*GROW4 + j16] = accM0;
      Gt[r1*GROW4 + j16] = accM1;
      if (done) {                 // mirror frozen M into LDS for the M^64 tail
        X4[r0*16 + j16] = accM0;
        X4[r1*16 + j16] = accM1;
      }
    }
    if (tid < 256) {
      int i = tid >> 2, j4 = tid & 3;
      float4 accN = B4[i*4 + j4];
      #pragma unroll 4
      for (int m = 0; m < 32; ++m) FNM4(accN, Kl[i*32 + m], CB4[m*4 + j4]);
      Gt[i*GROW4 + 16 + j4] = accN;
    } else {
      int z = tid - 256;
      int i = z >> 3, j4 = z & 7;
      Gt[i*GROW4 + 20 + j4]      = K4[i*8 + j4];
      Gt[(i+32)*GROW4 + 20 + j4] = K4[(i+32)*8 + j4];
    }
    __syncthreads();
    if (done) break;
  }

  // Tail: M64 = M^64 by 6 squarings (ping-pong Xl <-> Ppl)
  float* S_ = Xl;
  float* D_ = Ppl;
  #pragma unroll 1
  for (int q = 0; q < 6; ++q) {
    const float4* s4 = (const float4*)S_;
    float4 acc0 = make_float4(0,0,0,0), acc1 = make_float4(0,0,0,0);
    #pragma unroll 2
    for (int k4 = 0; k4 < 16; ++k4) {
      float4 a0 = s4[r0*16 + k4];
      float4 a1 = s4[r1*16 + k4];
      float4 p0 = s4[(4*k4+0)*16 + j16];
      float4 p1 = s4[(4*k4+1)*16 + j16];
      float4 p2 = s4[(4*k4+2)*16 + j16];
      float4 p3 = s4[(4*k4+3)*16 + j16];
      FMA4(acc0, a0.x, p0); FMA4(acc0, a0.y, p1); FMA4(acc0, a0.z, p2); FMA4(acc0, a0.w, p3);
      FMA4(acc1, a1.x, p0); FMA4(acc1, a1.y, p1); FMA4(acc1, a1.z, p2); FMA4(acc1, a1.w, p3);
    }
    __syncthreads();
    ((float4*)D_)[r0*16 + j16] = acc0;
    ((float4*)D_)[r1*16 + j16] = acc1;
    __syncthreads();
    float* tmp = S_; S_ = D_; D_ = tmp;
  }
  for (int x = tid; x < 4096; x += 512) M64g[x] = S_[x];
}

// ---------------------------------------------------------------------------
// Pass B: chunked recursion. block (c,b): 64 local steps; c=0 exact transient,
// c>=1 zero-init with frozen G. Stores local outputs + end-state d_c.
// ---------------------------------------------------------------------------
#define CSTEP(KK, CUR, NXT) do { \
  const int k_ = (KK); const int t_ = t0 + k_; \
  float uin = 0.f, zin = 0.f; \
  if (k_ + 1 < 64) { \
    if (i < 16)      uin = ins[((size_t)b*NT + t_ + 1)*NU + i]; \
    else if (i < 48) zin = obs[((size_t)b*NT + t_ + 1)*NO + (i - 16)]; \
  } \
  if (cz && t_ <= tconv) { \
    const float4* Gr = (const float4*)G + ((size_t)t_*64 + i)*GROW4; \
    _Pragma("unroll") \
    for (int k = 0; k < GROW4; ++k) g[k] = Gr[k]; \
  } \
  float a0 = 0.f, a1 = 0.f, a2 = 0.f, a3 = 0.f; \
  _Pragma("unroll") \
  for (int k = 0; k < GROW4; k += 4) { \
    float4 v0 = (CUR)[k], v1 = (CUR)[k+1], v2 = (CUR)[k+2], v3 = (CUR)[k+3]; \
    a0 = fmaf(g[k].x,   v0.x, a0); a0 = fmaf(g[k].y,   v0.y, a0); \
    a0 = fmaf(g[k].z,   v0.z, a0); a0 = fmaf(g[k].w,   v0.w, a0); \
    a1 = fmaf(g[k+1].x, v1.x, a1); a1 = fmaf(g[k+1].y, v1.y, a1); \
    a1 = fmaf(g[k+1].z, v1.z, a1); a1 = fmaf(g[k+1].w, v1.w, a1); \
    a2 = fmaf(g[k+2].x, v2.x, a2); a2 = fmaf(g[k+2].y, v2.y, a2); \
    a2 = fmaf(g[k+2].z, v2.z, a2); a2 = fmaf(g[k+2].w, v2.w, a2); \
    a3 = fmaf(g[k+3].x, v3.x, a3); a3 = fmaf(g[k+3].y, v3.y, a3); \
    a3 = fmaf(g[k+3].z, v3.z, a3); a3 = fmaf(g[k+3].w, v3.w, a3); \
  } \
  float acc = (a0 + a1) + (a2 + a3); \
  float* ny = (float*)(NXT); \
  ny[i] = acc; \
  if (i < 16) ny[64 + i] = uin; else if (i < 48) ny[80 + (i - 16)] = zin; \
  out[((size_t)b*(NT+1) + t_ + 1)*NS + i] = acc; \
  __syncthreads(); \
} while(0)

__global__ __launch_bounds__(64) void chunk_kernel(
    const float* __restrict__ obs, const float* __restrict__ ins,
    const float* __restrict__ x0, const float* __restrict__ G,
    const int* __restrict__ hdr, float* __restrict__ out,
    float* __restrict__ Dws)
{
  const int c = blockIdx.x;
  const int b = blockIdx.y;
  const int i = threadIdx.x;
  const int tconv = hdr[0];
  const bool cz = (c == 0);
  const int t0 = c * 64;
  __shared__ float4 y4[2][GROW4];
  float* y0 = (float*)y4[0];
  float4 g[GROW4];

  if (cz) {
    float xi = x0[i];
    y0[i] = xi;
    out[(size_t)b*(NT+1)*NS + i] = xi;
  } else {
    y0[i] = 0.f;
    const float4* Gr = (const float4*)G + ((size_t)tconv*64 + i)*GROW4;
    #pragma unroll
    for (int k = 0; k < GROW4; ++k) g[k] = Gr[k];
  }
  if (i < 16)      y0[64 + i]        = ins[((size_t)b*NT + t0)*NU + i];
  else if (i < 48) y0[80 + (i - 16)] = obs[((size_t)b*NT + t0)*NO + (i - 16)];
  __syncthreads();

  #pragma unroll 1
  for (int k = 0; k < 64; k += 2) {
    CSTEP(k,     y4[0], y4[1]);
    CSTEP(k + 1, y4[1], y4[0]);
  }
  Dws[((size_t)c*NB + b)*NS + i] = ((float*)y4[0])[i];   // end-state d_c
}

// ---------------------------------------------------------------------------
// Pass C: boundary scan. s_{c+1} = M64*s_c + d_c ; slot c := s_c.
// ---------------------------------------------------------------------------
__global__ __launch_bounds__(64) void bscan_kernel(
    const float* __restrict__ M64g, float* __restrict__ Dws)
{
  const int b = blockIdx.x;
  const int i = threadIdx.x;
  __shared__ float sv[64];
  float4 m[16];
  const float4* M4 = (const float4*)M64g + i*16;
  #pragma unroll
  for (int k = 0; k < 16; ++k) m[k] = M4[k];
  float s = Dws[(size_t)b*NS + i];          // s_1 (true chunk-0 end)
  #pragma unroll 1
  for (int c = 1; c < NCH; ++c) {
    sv[i] = s;
    __syncthreads();
    float d = Dws[((size_t)c*NB + b)*NS + i];
    Dws[((size_t)c*NB + b)*NS + i] = s;     // publish s_c for pass D
    const float4* cv = (const float4*)sv;
    float a0=0.f, a1=0.f, a2=0.f, a3=0.f;
    #pragma unroll
    for (int q = 0; q < 16; q += 4) {
      float4 y0=cv[q], y1=cv[q+1], y2=cv[q+2], y3=cv[q+3];
      a0=fmaf(m[q].x,y0.x,a0);   a0=fmaf(m[q].y,y0.y,a0);   a0=fmaf(m[q].z,y0.z,a0);   a0=fmaf(m[q].w,y0.w,a0);
      a1=fmaf(m[q+1].x,y1.x,a1); a1=fmaf(m[q+1].y,y1.y,a1); a1=fmaf(m[q+1].z,y1.z,a1); a1=fmaf(m[q+1].w,y1.w,a1);
      a2=fmaf(m[q+2].x,y2.x,a2); a2=fmaf(m[q+2].y,y2.y,a2); a2=fmaf(m[q+2].z,y2.z,a2); a2=fmaf(m[q+2].w,y2.w,a2);
      a3=fmaf(m[q+3].x,y3.x,a3); a3=fmaf(m[q+3].y,y3.y,a3); a3=fmaf(m[q+3].z,y3.z,a3); a3=fmaf(m[q+3].w,y3.w,a3);
    }
    s = ((a0+a1)+(a2+a3)) + d;              // s_{c+1}
    __syncthreads();
  }
}

// ---------------------------------------------------------------------------
// Pass D: correction. block (c,b), c=1..15: out[64c+k] += M^k * s_c.
// M row in registers; v ping-pong in LDS.
// ---------------------------------------------------------------------------
__global__ __launch_bounds__(64) void corr_kernel(
    const float* __restrict__ G, const int* __restrict__ hdr,
    const float* __restrict__ Dws, float* __restrict__ out)
{
  const int c = blockIdx.x + 1;             // 1..15
  const int b = blockIdx.y;
  const int i = threadIdx.x;
  const int tconv = hdr[0];
  __shared__ float sv[2][64];
  float4 m[16];
  const float4* Mr = (const float4*)(G + ((size_t)tconv*64 + i)*GROW);
  #pragma unroll
  for (int k = 0; k < 16; ++k) m[k] = Mr[k];
  sv[0][i] = Dws[((size_t)c*NB + b)*NS + i];   // s_c
  __syncthreads();
  float* outb = out + ((size_t)b*(NT+1) + (size_t)c*64)*NS;
  #pragma unroll 1
  for (int k = 1; k <= 64; ++k) {
    const float4* cv = (const float4*)sv[(k-1)&1];
    float a0=0.f, a1=0.f, a2=0.f, a3=0.f;
    #pragma unroll
    for (int q = 0; q < 16; q += 4) {
      float4 y0=cv[q], y1=cv[q+1], y2=cv[q+2], y3=cv[q+3];
      a0=fmaf(m[q].x,y0.x,a0);   a0=fmaf(m[q].y,y0.y,a0);   a0=fmaf(m[q].z,y0.z,a0);   a0=fmaf(m[q].w,y0.w,a0);
      a1=fmaf(m[q+1].x,y1.x,a1); a1=fmaf(m[q+1].y,y1.y,a1); a1=fmaf(m[q+1].z,y1.z,a1); a1=fmaf(m[q+1].w,y1.w,a1);
      a2=fmaf(m[q+2].x,y2.x,a2); a2=fmaf(m[q+2].y,y2.y,a2); a2=fmaf(m[q+2].z,y2.z,a2); a2=fmaf(m[q+2].w,y2.w,a2);
      a3=fmaf(m[q+3].x,y3.x,a3); a3=fmaf(m[q+3].y,y3.y,a3); a3=fmaf(m[q+3].z,y3.z,a3); a3=fmaf(m[q+3].w,y3.w,a3);
    }
    float nv = (a0+a1)+(a2+a3);
    sv[k&1][i] = nv;
    outb[(size_t)k*NS + i] += nv;
    __syncthreads();
  }
}

// ---------------------------------------------------------------------------
// Fallback serial xrec (used only if d_ws is too small for the scan path).
// ---------------------------------------------------------------------------
#define XSTEP(T, CUR, NXT) do { \
  const int t_ = (T); \
  float uin = 0.f, zin = 0.f; \
  if (t_ + 1 < NT) { \
    if (i < 16)      uin = ins[((size_t)b*NT + t_ + 1)*NU + i]; \
    else if (i < 48) zin = obs[((size_t)b*NT + t_ + 1)*NO + (i - 16)]; \
  } \
  if (t_ <= tconv) { \
    const float4* Gr = (const float4*)G + ((size_t)t_*64 + i)*GROW4; \
    _Pragma("unroll") \
    for (int k = 0; k < GROW4; ++k) g[k] = Gr[k]; \
  } \
  float a0 = 0.f, a1 = 0.f, a2 = 0.f, a3 = 0.f; \
  _Pragma("unroll") \
  for (int k = 0; k < GROW4; k += 4) { \
    float4 v0 = (CUR)[k], v1 = (CUR)[k+1], v2 = (CUR)[k+2], v3 = (CUR)[k+3]; \
    a0 = fmaf(g[k].x,   v0.x, a0); a0 = fmaf(g[k].y,   v0.y, a0); \
    a0 = fmaf(g[k].z,   v0.z, a0); a0 = fmaf(g[k].w,   v0.w, a0); \
    a1 = fmaf(g[k+1].x, v1.x, a1); a1 = fmaf(g[k+1].y, v1.y, a1); \
    a1 = fmaf(g[k+1].z, v1.z, a1); a1 = fmaf(g[k+1].w, v1.w, a1); \
    a2 = fmaf(g[k+2].x, v2.x, a2); a2 = fmaf(g[k+2].y, v2.y, a2); \
    a2 = fmaf(g[k+2].z, v2.z, a2); a2 = fmaf(g[k+2].w, v2.w, a2); \
    a3 = fmaf(g[k+3].x, v3.x, a3); a3 = fmaf(g[k+3].y, v3.y, a3); \
    a3 = fmaf(g[k+3].z, v3.z, a3); a3 = fmaf(g[k+3].w, v3.w, a3); \
  } \
  float acc = (a0 + a1) + (a2 + a3); \
  float* ny = (float*)(NXT); \
  ny[i] = acc; \
  if (i < 16) ny[64 + i] = uin; else if (i < 48) ny[80 + (i - 16)] = zin; \
  out[((size_t)b*(NT+1) + t_ + 1)*NS + i] = acc; \
  __syncthreads(); \
} while(0)

__global__ __launch_bounds__(64) void xrec_kernel(
    const float* __restrict__ obs, const float* __restrict__ ins,
    const float* __restrict__ x0, const float* __restrict__ G,
    const int* __restrict__ hdr, float* __restrict__ out)
{
  const int b = blockIdx.x;
  const int i = threadIdx.x;
  const int tconv = hdr[0];
  __shared__ float4 y4[2][GROW4];
  float* y0 = (float*)y4[0];

  float xi = x0[i];
  y0[i] = xi;
  out[(size_t)b*(NT+1)*NS + i] = xi;
  if (i < 16)      y0[64 + i]        = ins[(size_t)b*NT*NU + i];
  else if (i < 48) y0[80 + (i - 16)] = obs[(size_t)b*NT*NO + (i - 16)];
  __syncthreads();

  float4 g[GROW4];
  #pragma unroll 1
  for (int t = 0; t < NT; t += 2) {
    XSTEP(t,     y4[0], y4[1]);
    XSTEP(t + 1, y4[1], y4[0]);
  }
}

extern "C" void kernel_launch(void* const* d_in, const int* in_sizes, int n_in,
                              void* d_out, int out_size, void* d_ws, size_t ws_size,
                              hipStream_t stream) {
  const float* obs = (const float*)d_in[0];
  const float* ins = (const float*)d_in[1];
  const float* A   = (const float*)d_in[2];
  const float* Bm  = (const float*)d_in[3];
  const float* C   = (const float*)d_in[4];
  const float* Q   = (const float*)d_in[5];
  const float* R   = (const float*)d_in[6];
  const float* x0  = (const float*)d_in[7];
  float* out = (float*)d_out;

  int*   hdr  = (int*)d_ws;
  float* G    = (float*)((char*)d_ws + WS_G);
  float* M64g = (float*)((char*)d_ws + WS_M64);
  float* Dws  = (float*)((char*)d_ws + WS_D);

  int tcap = TCAP;
  if (ws_size < (size_t)NEED_G) {
    size_t per_t = (size_t)64 * GROW * sizeof(float);
    tcap = (int)((ws_size - 256) / per_t);
    if (tcap < 1) tcap = 1;
  }

  hipFuncSetAttribute((const void*)riccati_kernel,
                      hipFuncAttributeMaxDynamicSharedMemorySize,
                      LDS_FLOATS * sizeof(float));
  riccati_kernel<<<1, 512, LDS_FLOATS * sizeof(float), stream>>>(
      A, Bm, C, Q, R, G, M64g, hdr, tcap);

  if (ws_size >= (size_t)NEED_FULL) {
    chunk_kernel<<<dim3(NCH, NB), 64, 0, stream>>>(obs, ins, x0, G, hdr, out, Dws);
    bscan_kernel<<<NB, 64, 0, stream>>>(M64g, Dws);
    corr_kernel<<<dim3(NCH - 1, NB), 64, 0, stream>>>(G, hdr, Dws, out);
  } else {
    xrec_kernel<<<NB, 64, 0, stream>>>(obs, ins, x0, G, hdr, out);
  }
}